// Round 1
// baseline (223.565 us; speedup 1.0000x reference)
//
#include <hip/hip_runtime.h>

#define SEPS 1e-10f

__device__ __forceinline__ float fast_rcp(float x) { return __builtin_amdgcn_rcpf(x); }
__device__ __forceinline__ float fast_exp(float x) { return __expf(x); }
__device__ __forceinline__ float fast_sigmoid(float x) {
    return fast_rcp(1.0f + fast_exp(-x));
}

__global__ __launch_bounds__(256) void sinkhorn_mlp_kernel(
    const float* __restrict__ margins,
    const float* __restrict__ W1, const float* __restrict__ b1,
    const float* __restrict__ W2, const float* __restrict__ b2,
    const float* __restrict__ W3, const float* __restrict__ b3,
    const float* __restrict__ W4, const float* __restrict__ b4,
    float* __restrict__ out_mus, float* __restrict__ out_V, int n)
{
    int r = blockIdx.x * blockDim.x + threadIdx.x;
    if (r >= n) return;

    // ---- load margins (6 floats, 8B-aligned) ----
    const float2* mp = reinterpret_cast<const float2*>(margins + (size_t)r * 6);
    float2 mv0 = mp[0], mv1 = mp[1], mv2 = mp[2];
    float m[6] = {mv0.x, mv0.y, mv1.x, mv1.y, mv2.x, mv2.y};

    // ---- layer 1: 6 -> 64, relu ----
    // Weight indices are thread-uniform -> compiler should emit s_load (SGPR
    // broadcast), keeping the FMA as v_fma_f32 vdst, s_w, v_h, vdst.
    float h1[64];
#pragma unroll 8
    for (int j = 0; j < 64; ++j) {
        float acc = b1[j];
#pragma unroll
        for (int k = 0; k < 6; ++k) acc = fmaf(m[k], W1[k * 64 + j], acc);
        h1[j] = fmaxf(acc, 0.0f);
    }

    // ---- layer 2: 64 -> 32, relu (dominant cost: 2048 FMA) ----
    float h2[32];
#pragma unroll 4
    for (int j = 0; j < 32; ++j) {
        float acc = b2[j];
#pragma unroll
        for (int k = 0; k < 64; ++k) acc = fmaf(h1[k], W2[k * 32 + j], acc);
        h2[j] = fmaxf(acc, 0.0f);
    }

    // ---- layer 3: 32 -> 16, relu ----
    float h3[16];
#pragma unroll 4
    for (int j = 0; j < 16; ++j) {
        float acc = b3[j];
#pragma unroll
        for (int k = 0; k < 32; ++k) acc = fmaf(h2[k], W3[k * 16 + j], acc);
        h3[j] = fmaxf(acc, 0.0f);
    }

    // ---- layer 4: 16 -> 9, linear ----
    float pars[9];
#pragma unroll
    for (int j = 0; j < 9; ++j) {
        float acc = b4[j];
#pragma unroll
        for (int k = 0; k < 16; ++k) acc = fmaf(h3[k], W4[k * 9 + j], acc);
        pars[j] = acc;
    }

    // ---- heads ----
    float p0 = fast_exp(pars[0]);
    float p1 = fast_exp(pars[1]);
    float p2 = fast_exp(pars[2]);
    float p3 = fast_exp(pars[3]);

    // muc[i][j] = p3 * p[|i-j|]
    float A00 = p3 * p0, A01 = p3 * p1, A02 = p3 * p2;
    float A10 = p3 * p1, A11 = p3 * p0, A12 = p3 * p1;
    float A20 = p3 * p2, A21 = p3 * p1, A22 = p3 * p0;

    float sm0 = fast_sigmoid(pars[4]);
    float sm1 = fast_sigmoid(pars[5]);
    float sf0 = fast_sigmoid(pars[6]);
    float sf1 = fast_sigmoid(pars[7]);
    float V   = fast_exp(pars[8]);

    float M0 = m[0], M1 = m[1], M2 = m[2];
    float F0 = m[3], F1 = m[4], F2 = m[5];

    // shm0 = [sm0, sm1, 1]; shf0 = [sf0, sf1, 1]
    float rc0 = M0 * sm0, rc1 = M1 * sm1, rc2 = M2;   // mucm0 (row targets)
    float cc0 = F0 * sf0, cc1 = F1 * sf1, cc2 = F2;   // muc0f (col targets)
    float mum0_0 = M0 * (1.0f - sm0);
    float mum0_1 = M1 * (1.0f - sm1);
    float mum0_2 = 0.0f;                               // M2 * (1-1)
    float mu0f_0 = F0 * (1.0f - sf0);
    float mu0f_1 = F1 * (1.0f - sf1);
    float mu0f_2 = 0.0f;

    // ---- Sinkhorn: 10 iterations of row-normalize then col-normalize ----
#pragma unroll
    for (int it = 0; it < 10; ++it) {
        float f0 = rc0 * fast_rcp(A00 + A01 + A02 + SEPS);
        float f1 = rc1 * fast_rcp(A10 + A11 + A12 + SEPS);
        float f2 = rc2 * fast_rcp(A20 + A21 + A22 + SEPS);
        A00 *= f0; A01 *= f0; A02 *= f0;
        A10 *= f1; A11 *= f1; A12 *= f1;
        A20 *= f2; A21 *= f2; A22 *= f2;
        float g0 = cc0 * fast_rcp(A00 + A10 + A20 + SEPS);
        float g1 = cc1 * fast_rcp(A01 + A11 + A21 + SEPS);
        float g2 = cc2 * fast_rcp(A02 + A12 + A22 + SEPS);
        A00 *= g0; A10 *= g0; A20 *= g0;
        A01 *= g1; A11 *= g1; A21 *= g1;
        A02 *= g2; A12 *= g2; A22 *= g2;
    }

    // ---- output: mus (4x4 row-major) then V ----
    float4* o = reinterpret_cast<float4*>(out_mus + (size_t)r * 16);
    o[0] = make_float4(A00, A01, A02, mum0_0);
    o[1] = make_float4(A10, A11, A12, mum0_1);
    o[2] = make_float4(A20, A21, A22, mum0_2);
    o[3] = make_float4(mu0f_0, mu0f_1, mu0f_2, 0.0f);
    out_V[r] = V;
}

extern "C" void kernel_launch(void* const* d_in, const int* in_sizes, int n_in,
                              void* d_out, int out_size, void* d_ws, size_t ws_size,
                              hipStream_t stream) {
    const float* margins = (const float*)d_in[0];
    const float* W1 = (const float*)d_in[1];
    const float* b1 = (const float*)d_in[2];
    const float* W2 = (const float*)d_in[3];
    const float* b2 = (const float*)d_in[4];
    const float* W3 = (const float*)d_in[5];
    const float* b3 = (const float*)d_in[6];
    const float* W4 = (const float*)d_in[7];
    const float* b4 = (const float*)d_in[8];

    int n = in_sizes[0] / 6;
    float* out_mus = (float*)d_out;
    float* out_V   = out_mus + (size_t)n * 16;

    dim3 block(256);
    dim3 grid((n + 255) / 256);
    sinkhorn_mlp_kernel<<<grid, block, 0, stream>>>(
        margins, W1, b1, W2, b2, W3, b3, W4, b4, out_mus, out_V, n);
}